// Round 3
// baseline (747.285 us; speedup 1.0000x reference)
//
#include <hip/hip_runtime.h>

typedef unsigned short u16;
typedef __attribute__((ext_vector_type(8))) short bf16x8;
typedef __attribute__((ext_vector_type(4))) float f32x4;

union U8 { unsigned int w[4]; bf16x8 v; };

#define LEAKY 0.2f
#define LN_EPS 1e-5f
#define NTILES 20000   // 640000 edges / 32 per wave-tile
#define NWAVES 2048    // 256 blocks x 8 waves

// fp32 -> bf16 RTNE
__device__ __forceinline__ u16 f2bf(float f) {
  union { float f; unsigned int u; } a; a.f = f;
  unsigned int u = a.u;
  return (u16)((u + 0x7fffu + ((u >> 16) & 1u)) >> 16);
}
__device__ __forceinline__ unsigned int pk2(float lo, float hi) {
  return (unsigned int)f2bf(lo) | ((unsigned int)f2bf(hi) << 16);
}

// Build the 128KB weight fragment image in ws, in EXACT per-MFMA fragment
// order: frag f (0..127) is a 1KB block; within it lane l (0..63) holds 8
// contiguous bf16 (16B -> one conflict-free ds_read_b128).
// f = base + c*8 + n;  bases: W1=0 (c 0..7), W2=64 (c 0..3), W3=96 (c 0..3).
// Element (f, l, i):  p=l&15, q=l>>4, j=i&3, h=i>>2 ->
//   W[16n+p][32c + 4q + j + 16h]     (torch [out][in] row-major)
__global__ void build_wfrag(const float* __restrict__ W1,
                            const float* __restrict__ W2,
                            const float* __restrict__ W3,
                            u16* __restrict__ wout) {
  int id = blockIdx.x * 256 + threadIdx.x;     // 0..65535
  int f = id >> 9, l = (id >> 3) & 63, i = id & 7;
  int p = l & 15, q = l >> 4, j = i & 3, h = i >> 2;
  const float* W; int c, K;
  if (f < 64)      { W = W1; c = f >> 3;        K = 256; }
  else if (f < 96) { W = W2; c = (f - 64) >> 3; K = 128; }
  else             { W = W3; c = (f - 96) >> 3; K = 128; }
  int n = f & 7;
  wout[id] = f2bf(W[(16 * n + p) * K + 32 * c + 4 * q + j + 16 * h]);
}

// gather one edge's [x[dest] | x[src]] row (per-lane slice) into 8 bf16 frags
// xr0/xr1 already include +4q float offset
__device__ __forceinline__ void gather16(const float* __restrict__ xr0,
                                         const float* __restrict__ xr1,
                                         U8* mf) {
  float4 g[16];
  const float4* a = (const float4*)xr0;
  const float4* b = (const float4*)xr1;
  #pragma unroll
  for (int c = 0; c < 4; ++c) {
    g[2 * c]     = a[8 * c];
    g[2 * c + 1] = a[8 * c + 4];
    g[8 + 2 * c] = b[8 * c];
    g[9 + 2 * c] = b[8 * c + 4];
  }
  #pragma unroll
  for (int c = 0; c < 8; ++c) {
    mf[c].w[0] = pk2(g[2 * c].x,     g[2 * c].y);
    mf[c].w[1] = pk2(g[2 * c].z,     g[2 * c].w);
    mf[c].w[2] = pk2(g[2 * c + 1].x, g[2 * c + 1].y);
    mf[c].w[3] = pk2(g[2 * c + 1].z, g[2 * c + 1].w);
  }
}

// leaky-relu acc in place, then pack to bf16 B-frags for the next layer:
// frag c2 elem i  <->  chan 32c2 + 4q + (i&3) + 16(i>>2)  = acc[2c2+(i>>2)][i&3]
__device__ __forceinline__ void leaky_pack(f32x4* acc, U8* hf) {
  #pragma unroll
  for (int n = 0; n < 8; ++n) {
    #pragma unroll
    for (int j = 0; j < 4; ++j) {
      float v = acc[n][j];
      acc[n][j] = (v >= 0.f) ? v : LEAKY * v;
    }
  }
  #pragma unroll
  for (int c = 0; c < 4; ++c) {
    hf[c].w[0] = pk2(acc[2 * c][0],     acc[2 * c][1]);
    hf[c].w[1] = pk2(acc[2 * c][2],     acc[2 * c][3]);
    hf[c].w[2] = pk2(acc[2 * c + 1][0], acc[2 * c + 1][1]);
    hf[c].w[3] = pk2(acc[2 * c + 1][2], acc[2 * c + 1][3]);
  }
}

// one layer: B-frag (W) read once from LDS, used for BOTH row tiles
template <int FBASE, int NC>
__device__ __forceinline__ void gemm(const u16* __restrict__ wlds, int lane,
                                     const U8* mfA, const U8* mfB,
                                     f32x4* accA, f32x4* accB) {
  #pragma unroll
  for (int c = 0; c < NC; ++c) {
    #pragma unroll
    for (int n = 0; n < 8; ++n) {
      U8 wf;
      wf.v = *(const bf16x8*)(wlds + ((FBASE + c * 8 + n) << 9) + (lane << 3));
      accA[n] = __builtin_amdgcn_mfma_f32_16x16x32_bf16(wf.v, mfA[c].v, accA[n], 0, 0, 0);
      accB[n] = __builtin_amdgcn_mfma_f32_16x16x32_bf16(wf.v, mfB[c].v, accB[n], 0, 0, 0);
    }
  }
}

// LayerNorm one 16-edge tile held as acc[n][j] = h[edge p][chan 16n+4q+j]
__device__ __forceinline__ void ln_store(const f32x4* acc, const f32x4* par,
                                         int q, float* __restrict__ orow) {
  float s = 0.f, ss = 0.f;
  #pragma unroll
  for (int n = 0; n < 8; ++n) {
    #pragma unroll
    for (int j = 0; j < 4; ++j) { float v = acc[n][j]; s += v; ss += v * v; }
  }
  s += __shfl_xor(s, 16, 64);  ss += __shfl_xor(ss, 16, 64);
  s += __shfl_xor(s, 32, 64);  ss += __shfl_xor(ss, 32, 64);
  float mean = s * (1.f / 128.f);
  float var  = ss * (1.f / 128.f) - mean * mean;
  float inv  = rsqrtf(var + LN_EPS);
  f32x4* o4 = (f32x4*)orow;
  #pragma unroll
  for (int n = 0; n < 8; ++n) {
    f32x4 gm = par[(n * 4 + q) * 4 + 2];
    f32x4 bt = par[(n * 4 + q) * 4 + 3];
    f32x4 r;
    r[0] = (acc[n][0] - mean) * inv * gm[0] + bt[0];
    r[1] = (acc[n][1] - mean) * inv * gm[1] + bt[1];
    r[2] = (acc[n][2] - mean) * inv * gm[2] + bt[2];
    r[3] = (acc[n][3] - mean) * inv * gm[3] + bt[3];
    __builtin_nontemporal_store(r, o4 + 4 * n);
  }
}

__global__ __launch_bounds__(512, 2) void edge_mlp(
    const float* __restrict__ x, const int* __restrict__ ei,
    const float* __restrict__ b1, const float* __restrict__ b2,
    const float* __restrict__ gamma, const float* __restrict__ beta,
    const u16* __restrict__ wbf, float* __restrict__ out, int E) {

  __shared__ __align__(16) u16 wlds[65536];   // 128 KB weight frags
  __shared__ __align__(16) float wpar[512];   // b1|b2|gamma|beta frag table

  const int tid = threadIdx.x;
  // stage all weights once (persistent block)
  {
    const uint4* s = (const uint4*)wbf;
    uint4* d = (uint4*)wlds;
    #pragma unroll
    for (int i = 0; i < 16; ++i) d[tid + i * 512] = s[tid + i * 512];
  }
  if (tid < 512) {
    int n = tid >> 6, q = (tid >> 4) & 3, prm = (tid >> 2) & 3, j = tid & 3;
    int col = 16 * n + 4 * q + j;
    const float* src = (prm == 0) ? b1 : (prm == 1) ? b2 : (prm == 2) ? gamma : beta;
    wpar[tid] = src[col];
  }
  __syncthreads();
  // no further barriers: each wave is fully independent

  const int lane = tid & 63;
  const int p = lane & 15, q = lane >> 4;
  const int wid = (blockIdx.x << 3) | (tid >> 6);
  const f32x4* par = (const f32x4*)wpar;   // cell index (n*4+q)*4 + prm

  for (int t = wid; t < NTILES; t += NWAVES) {
    const int e0 = t * 32;
    const long nd0 = ei[E + e0 + p],      ns0 = ei[e0 + p];
    const long nd1 = ei[E + e0 + 16 + p], ns1 = ei[e0 + 16 + p];

    U8 mfA[8], mfB[8];
    gather16(x + nd0 * 128 + 4 * q, x + ns0 * 128 + 4 * q, mfA);
    gather16(x + nd1 * 128 + 4 * q, x + ns1 * 128 + 4 * q, mfB);

    f32x4 accA[8], accB[8];
    // ---- GEMM1: acc init = b1, K=256 (c 0..7) ----
    #pragma unroll
    for (int n = 0; n < 8; ++n) {
      f32x4 b = par[(n * 4 + q) * 4 + 0];
      accA[n] = b; accB[n] = b;
    }
    gemm<0, 8>(wlds, lane, mfA, mfB, accA, accB);
    U8 hfA[4], hfB[4];
    leaky_pack(accA, hfA);
    leaky_pack(accB, hfB);

    // ---- GEMM2: init = b2, K=128 (c 0..3) ----
    #pragma unroll
    for (int n = 0; n < 8; ++n) {
      f32x4 b = par[(n * 4 + q) * 4 + 1];
      accA[n] = b; accB[n] = b;
    }
    gemm<64, 4>(wlds, lane, hfA, hfB, accA, accB);
    leaky_pack(accA, hfA);
    leaky_pack(accB, hfB);

    // ---- GEMM3: no bias, K=128 ----
    #pragma unroll
    for (int n = 0; n < 8; ++n) { accA[n] = (f32x4)(0.f); accB[n] = (f32x4)(0.f); }
    gemm<96, 4>(wlds, lane, hfA, hfB, accA, accB);

    // ---- LayerNorm + store ----
    ln_store(accA, par, q, out + (long)(e0 + p) * 128 + 4 * q);
    ln_store(accB, par, q, out + (long)(e0 + 16 + p) * 128 + 4 * q);
  }
}

extern "C" void kernel_launch(void* const* d_in, const int* in_sizes, int n_in,
                              void* d_out, int out_size, void* d_ws, size_t ws_size,
                              hipStream_t stream) {
  const float* x     = (const float*)d_in[0];
  const int*   ei    = (const int*)d_in[1];
  const float* W1    = (const float*)d_in[2];
  const float* b1    = (const float*)d_in[3];
  const float* W2    = (const float*)d_in[4];
  const float* b2    = (const float*)d_in[5];
  const float* W3    = (const float*)d_in[6];
  const float* gamma = (const float*)d_in[7];
  const float* beta  = (const float*)d_in[8];
  const int E = in_sizes[1] / 2;   // 640000
  u16* wbf = (u16*)d_ws;           // 128 KB fragment image

  build_wfrag<<<256, 256, 0, stream>>>(W1, W2, W3, wbf);
  edge_mlp<<<256, 512, 0, stream>>>(x, ei, b1, b2, gamma, beta, wbf,
                                    (float*)d_out, E);
}